// Round 7
// baseline (512.651 us; speedup 1.0000x reference)
//
#include <hip/hip_runtime.h>

// OpenLSTM: B=64, T=8192, nstep=4096, HIDDEN=16, PROJ=2, INPUT=2
// Phase 1 (t<4096): parallel, gates from W_ih@x+b only, c1=i*g.
// Phase 2 (t>=4096): sequential scan, latency/issue-bound on 16 CUs.
//   r7: unit-major quad layout (r6-proven) + C-state prescale (drop 1 chain
//   mul) + branchless same-address store + clock-keeper spinner blocks
//   (cycle-budgeted VALU work on idle CUs to hold the high DPM state;
//   r6 showed active-CU VALU ~100% busy but wall-time implies ~1.2-1.5GHz).

#define BB   64
#define TT   8192
#define NST  4096
#define PF   16
#define NSPIN      224
#define SPIN_ITERS 36000   // x16 issue-cyc ~= 576K cyc ~= scan cycle budget

static __device__ __forceinline__ float fast_exp2(float x) {
#if __has_builtin(__builtin_amdgcn_exp2f)
  return __builtin_amdgcn_exp2f(x);
#else
  return exp2f(x);
#endif
}
static __device__ __forceinline__ float fast_rcp(float x) {
#if __has_builtin(__builtin_amdgcn_rcpf)
  return __builtin_amdgcn_rcpf(x);
#else
  return 1.0f / x;
#endif
}

// x + dpp_perm(x): CTRL = row_ror:N (0x120|N), row_bcast15 (0x142),
// row_bcast31 (0x143). Proven by r2/r5/r6 PASS.
template <int CTRL>
static __device__ __forceinline__ float rr_add(float x) {
  int r = __builtin_amdgcn_update_dpp(0, __builtin_bit_cast(int, x), CTRL, 0xF, 0xF, true);
  return x + __builtin_bit_cast(float, r);
}

// quad_perm broadcast of quad-lane Q to all 4 lanes of the quad (r6-proven).
template <int SEL>  // 0x00,0x55,0xAA,0xFF
static __device__ __forceinline__ float qperm(float x) {
  int r = __builtin_amdgcn_update_dpp(0, __builtin_bit_cast(int, x), SEL, 0xF, 0xF, true);
  return __builtin_bit_cast(float, r);
}

static __device__ __forceinline__ float rdlane63(float x) {
  return __builtin_bit_cast(float,
      __builtin_amdgcn_readlane(__builtin_bit_cast(int, x), 63));
}

// ---------------- scan (phase 2) per-lane state ----------------
struct SW {
  float w0, w1, wh0, wh1, b;        // this lane's gate row, pre-scaled
  float m, n;                        // activation affine (g-lane carries 2.885)
  float whr0, whr0m2, whr1, whr1m2;  // Whr[0,hh], -2*that, Whr[1,hh], -2*that
};

// State C = 2*log2(e) * c  (prescaled cell), h0,h1 wave-uniform SGPRs.
static __device__ __forceinline__ void scan_step(const SW& w, float x0, float x1,
                                                 float& h0, float& h1, float& C) {
  const float bse = fmaf(w.w1, x1, fmaf(w.w0, x0, w.b));      // off-chain
  float s = fmaf(w.wh0, h0, bse);
  s = fmaf(w.wh1, h1, s);
  const float d = fast_rcp(1.f + fast_exp2(s));
  const float a = fmaf(d, w.m, w.n);   // i,f,o: sigmoid; g: 2.885*tanh
  const float gi = qperm<0x00>(a);
  const float gf = qperm<0x55>(a);
  const float gg = qperm<0xAA>(a);     // = 2.885*g
  const float go = qperm<0xFF>(a);
  C = fmaf(gf, C, gi * gg);            // C = 2.885*c, quad-redundant
  const float o0  = go * w.whr0;       // off-chain vs exp2(C)
  const float o0m = go * w.whr0m2;
  const float o1  = go * w.whr1;
  const float o1m = go * w.whr1m2;
  const float r2 = fast_rcp(1.f + fast_exp2(C));
  float p0 = fmaf(r2, o0m, o0);        // = o*tanh(c)*Whr[0,hh]
  float p1 = fmaf(r2, o1m, o1);
  p0 = rr_add<0x124>(p0); p1 = rr_add<0x124>(p1);   // + ror4
  p0 = rr_add<0x128>(p0); p1 = rr_add<0x128>(p1);   // + ror8 (row sums)
  p0 = rr_add<0x142>(p0); p1 = rr_add<0x142>(p1);   // bcast15
  p0 = rr_add<0x143>(p0); p1 = rr_add<0x143>(p1);   // bcast31: lane63 total
  h0 = rdlane63(p0);
  h1 = rdlane63(p1);
}

__global__ __launch_bounds__(256) void openlstm_kernel(
    const float* __restrict__ u_train, const float* __restrict__ y_train,
    const float* __restrict__ Wih, const float* __restrict__ Whh,
    const float* __restrict__ bih, const float* __restrict__ bhh,
    const float* __restrict__ Whr, float* __restrict__ out) {
  const int tid = threadIdx.x;
  const float S1 = -1.4426950408889634f;   // -log2(e)
  const float S2 = -2.8853900817779268f;   // -2*log2(e)

  if (blockIdx.x < 16) {
    // ---------------- Phase 2: sequential scan ----------------
    const int lane = tid & 63;
    const int wv   = tid >> 6;                   // wave in block
    const int bb   = blockIdx.x * 4 + wv;        // batch 0..63
    const int hh   = lane >> 2;                  // unit 0..15
    const int r    = lane & 3;                   // gate 0..3 = i,f,g,o
    const int wrow = r * 16 + hh;                // reference gate row
    const bool isg = (r == 2);
    const float sc = isg ? S2 : S1;

    SW w;
    w.w0  = Wih[2 * wrow] * sc;  w.w1  = Wih[2 * wrow + 1] * sc;
    w.wh0 = Whh[2 * wrow] * sc;  w.wh1 = Whh[2 * wrow + 1] * sc;
    w.b   = (bih[wrow] + bhh[wrow]) * sc;
    // g-lane activation = 2.885*tanh -> C-state is prescaled by 2*log2(e)
    w.m   = isg ? 5.7707801635558536f : 1.f;
    w.n   = isg ? -2.8853900817779268f : 0.f;
    w.whr0   = Whr[hh];
    w.whr0m2 = -2.f * w.whr0;
    w.whr1   = Whr[16 + hh];
    w.whr1m2 = -2.f * w.whr1;

    float h0 = 0.f, h1 = 0.f, C = 0.f;
    {
      // initial carry from y_train[bb, NST-1, :]  (h=0, C=0 path)
      const float2 xv = *(const float2*)(y_train + ((size_t)bb * TT + (NST - 1)) * 2);
      scan_step(w, xv.x, xv.y, h0, h1, C);
    }

    const float* up = u_train + ((size_t)bb * TT + NST) * 2;
    float*       op = out     + ((size_t)bb * TT + NST) * 2;

    float2 xb[PF];
#pragma unroll
    for (int k = 0; k < PF; ++k) xb[k] = *(const float2*)(up + 2 * k);

#pragma unroll 1
    for (int t = 0; t < NST - PF; t += PF) {
#pragma unroll
      for (int k = 0; k < PF; ++k) {
        const float x0 = xb[k].x, x1 = xb[k].y;
        xb[k] = *(const float2*)(up + (size_t)(t + k + PF) * 2);  // prefetch
        scan_step(w, x0, x1, h0, h1, C);
        // h0,h1 wave-uniform: all lanes store same data to same address
        *(float2*)(op + (size_t)(t + k) * 2) = make_float2(h0, h1);
      }
    }
    // epilogue window (no prefetch)
#pragma unroll
    for (int k = 0; k < PF; ++k) {
      scan_step(w, xb[k].x, xb[k].y, h0, h1, C);
      *(float2*)(op + (size_t)(NST - PF + k) * 2) = make_float2(h0, h1);
    }
  } else if (blockIdx.x < 16 + NSPIN) {
    // ---------------- Clock-keeper spinners ----------------
    // Fixed cycle budget of issue-dense VALU work; self-calibrating to the
    // clock (ends ~when the scan ends at any SCLK). Keeps DPM state high.
    float a0 = (float)tid * 1e-9f + 1.00f;
    float a1 = (float)tid * 1e-9f + 1.01f;
    float a2 = (float)tid * 1e-9f + 1.02f;
    float a3 = (float)tid * 1e-9f + 1.03f;
    float a4 = (float)tid * 1e-9f + 1.04f;
    float a5 = (float)tid * 1e-9f + 1.05f;
    float a6 = (float)tid * 1e-9f + 1.06f;
    float a7 = (float)tid * 1e-9f + 1.07f;
    const float mu = 0.999999f, ad = 1e-7f;
#pragma unroll 4
    for (int i = 0; i < SPIN_ITERS; ++i) {
      a0 = fmaf(a0, mu, ad); a1 = fmaf(a1, mu, ad);
      a2 = fmaf(a2, mu, ad); a3 = fmaf(a3, mu, ad);
      a4 = fmaf(a4, mu, ad); a5 = fmaf(a5, mu, ad);
      a6 = fmaf(a6, mu, ad); a7 = fmaf(a7, mu, ad);
    }
    asm volatile("" :: "v"(a0), "v"(a1), "v"(a2), "v"(a3),
                       "v"(a4), "v"(a5), "v"(a6), "v"(a7));
  } else {
    // ---------------- Phase 1: parallel teacher-forced (r2/r5/r6-proven) --
    const int hh  = tid & 15;
    const int grp = tid >> 4;
    const int gid = (blockIdx.x - (16 + NSPIN)) * 16 + grp;  // 0 .. B*NST-1
    const int bb  = gid >> 12;                               // /4096
    const int t   = gid & (NST - 1);
    const int ri = hh, rg = hh + 32, ro = hh + 48;

    const float wii0 = Wih[2 * ri] * S1, wii1 = Wih[2 * ri + 1] * S1;
    const float wig0 = Wih[2 * rg] * S2, wig1 = Wih[2 * rg + 1] * S2;
    const float wio0 = Wih[2 * ro] * S1, wio1 = Wih[2 * ro + 1] * S1;
    const float bi = (bih[ri] + bhh[ri]) * S1;
    const float bg = (bih[rg] + bhh[rg]) * S2;
    const float bo = (bih[ro] + bhh[ro]) * S1;
    const float whr0 = Whr[hh], whr1 = Whr[16 + hh];

    const float2 xv = *(const float2*)(y_train + ((size_t)bb * TT + t) * 2);
    const float si = fmaf(wii1, xv.y, fmaf(wii0, xv.x, bi));
    const float sg = fmaf(wig1, xv.y, fmaf(wig0, xv.x, bg));
    const float so = fmaf(wio1, xv.y, fmaf(wio0, xv.x, bo));
    const float gi = fast_rcp(1.f + fast_exp2(si));
    const float gg = fmaf(2.f, fast_rcp(1.f + fast_exp2(sg)), -1.f);
    const float go = fast_rcp(1.f + fast_exp2(so));
    const float c1 = gi * gg;   // c0 = 0
    const float tc = fmaf(-2.f, fast_rcp(1.f + fast_exp2(c1 * 2.8853900817779268f)), 1.f);
    const float v  = go * tc;
    float p0 = v * whr0;
    float p1 = v * whr1;
    p0 = rr_add<0x128>(p0); p1 = rr_add<0x128>(p1);
    p0 = rr_add<0x124>(p0); p1 = rr_add<0x124>(p1);
    p0 = rr_add<0x122>(p0); p1 = rr_add<0x122>(p1);
    p0 = rr_add<0x121>(p0); p1 = rr_add<0x121>(p1);
    if (hh == 0) *(float2*)(out + ((size_t)bb * TT + t) * 2) = make_float2(p0, p1);
  }
}

extern "C" void kernel_launch(void* const* d_in, const int* in_sizes, int n_in,
                              void* d_out, int out_size, void* d_ws, size_t ws_size,
                              hipStream_t stream) {
  const float* u_train = (const float*)d_in[0];
  const float* y_train = (const float*)d_in[1];
  const float* Wih     = (const float*)d_in[2];
  const float* Whh     = (const float*)d_in[3];
  const float* bih     = (const float*)d_in[4];
  const float* bhh     = (const float*)d_in[5];
  const float* Whr     = (const float*)d_in[6];
  float* out = (float*)d_out;

  // blocks 0..15: scan; 16..239: clock-keeper spinners; rest: phase-1.
  const int grid = 16 + NSPIN + (BB * NST) / 16;
  openlstm_kernel<<<grid, 256, 0, stream>>>(u_train, y_train, Wih, Whh, bih,
                                            bhh, Whr, out);
}

// Round 8
// 499.016 us; speedup vs baseline: 1.0273x; 1.0273x over previous
//
#include <hip/hip_runtime.h>

// OpenLSTM: B=64, T=8192, nstep=4096, HIDDEN=16, PROJ=2, INPUT=2
// Phase 1 (t<4096): parallel, gates from W_ih@x+b only, c1=i*g.
// Phase 2 (t>=4096): sequential scan; 64 lanes/batch, unit-major quads,
//   quad_perm gate exchange + DPP rotation reduce + readlane broadcast.
//   r8: r7 step math w/o spinners (r7 post-mortem: SCLK pinned ~1.2GHz,
//   spinners only stole issue slots), + setprio(1) on scan waves,
//   + paired float4 load/store (1 VMEM each per 2 steps).

#define BB   64
#define TT   8192
#define NST  4096

static __device__ __forceinline__ float fast_exp2(float x) {
#if __has_builtin(__builtin_amdgcn_exp2f)
  return __builtin_amdgcn_exp2f(x);
#else
  return exp2f(x);
#endif
}
static __device__ __forceinline__ float fast_rcp(float x) {
#if __has_builtin(__builtin_amdgcn_rcpf)
  return __builtin_amdgcn_rcpf(x);
#else
  return 1.0f / x;
#endif
}

// x + dpp_perm(x): CTRL = row_ror:N (0x120|N), row_bcast15 (0x142),
// row_bcast31 (0x143). Proven by r2/r5/r6/r7 PASS.
template <int CTRL>
static __device__ __forceinline__ float rr_add(float x) {
  int r = __builtin_amdgcn_update_dpp(0, __builtin_bit_cast(int, x), CTRL, 0xF, 0xF, true);
  return x + __builtin_bit_cast(float, r);
}

// quad_perm broadcast of quad-lane Q to all 4 lanes of the quad (r6-proven).
template <int SEL>  // 0x00,0x55,0xAA,0xFF
static __device__ __forceinline__ float qperm(float x) {
  int r = __builtin_amdgcn_update_dpp(0, __builtin_bit_cast(int, x), SEL, 0xF, 0xF, true);
  return __builtin_bit_cast(float, r);
}

static __device__ __forceinline__ float rdlane63(float x) {
  return __builtin_bit_cast(float,
      __builtin_amdgcn_readlane(__builtin_bit_cast(int, x), 63));
}

// ---------------- scan (phase 2) per-lane state ----------------
struct SW {
  float w0, w1, wh0, wh1, b;        // this lane's gate row, pre-scaled
  float m, n;                        // activation affine (g-lane carries 2.885)
  float whr0, whr0m2, whr1, whr1m2;  // Whr[0,hh], -2*that, Whr[1,hh], -2*that
};

// State C = 2*log2(e) * c  (prescaled cell); h0,h1 wave-uniform.
static __device__ __forceinline__ void scan_step(const SW& w, float x0, float x1,
                                                 float& h0, float& h1, float& C) {
  const float bse = fmaf(w.w1, x1, fmaf(w.w0, x0, w.b));      // off-chain
  float s = fmaf(w.wh0, h0, bse);
  s = fmaf(w.wh1, h1, s);
  const float d = fast_rcp(1.f + fast_exp2(s));
  const float a = fmaf(d, w.m, w.n);   // i,f,o: sigmoid; g: 2.885*tanh
  const float gi = qperm<0x00>(a);
  const float gf = qperm<0x55>(a);
  const float gg = qperm<0xAA>(a);     // = 2.885*g
  const float go = qperm<0xFF>(a);
  C = fmaf(gf, C, gi * gg);            // C = 2.885*c, quad-redundant
  const float o0  = go * w.whr0;       // off-chain vs exp2(C)
  const float o0m = go * w.whr0m2;
  const float o1  = go * w.whr1;
  const float o1m = go * w.whr1m2;
  const float r2 = fast_rcp(1.f + fast_exp2(C));
  float p0 = fmaf(r2, o0m, o0);        // = o*tanh(c)*Whr[0,hh]
  float p1 = fmaf(r2, o1m, o1);
  p0 = rr_add<0x124>(p0); p1 = rr_add<0x124>(p1);   // + ror4
  p0 = rr_add<0x128>(p0); p1 = rr_add<0x128>(p1);   // + ror8 (row sums)
  p0 = rr_add<0x142>(p0); p1 = rr_add<0x142>(p1);   // bcast15
  p0 = rr_add<0x143>(p0); p1 = rr_add<0x143>(p1);   // bcast31: lane63 total
  h0 = rdlane63(p0);
  h1 = rdlane63(p1);
}

__global__ __launch_bounds__(256) void openlstm_kernel(
    const float* __restrict__ u_train, const float* __restrict__ y_train,
    const float* __restrict__ Wih, const float* __restrict__ Whh,
    const float* __restrict__ bih, const float* __restrict__ bhh,
    const float* __restrict__ Whr, float* __restrict__ out) {
  const int tid = threadIdx.x;
  const float S1 = -1.4426950408889634f;   // -log2(e)
  const float S2 = -2.8853900817779268f;   // -2*log2(e)

  if (blockIdx.x < 16) {
    // ---------------- Phase 2: sequential scan ----------------
    __builtin_amdgcn_s_setprio(1);           // shield from phase-1 block churn
    const int lane = tid & 63;
    const int wv   = tid >> 6;                   // wave in block
    const int bb   = blockIdx.x * 4 + wv;        // batch 0..63
    const int hh   = lane >> 2;                  // unit 0..15
    const int r    = lane & 3;                   // gate 0..3 = i,f,g,o
    const int wrow = r * 16 + hh;                // reference gate row
    const bool isg = (r == 2);
    const float sc = isg ? S2 : S1;

    SW w;
    w.w0  = Wih[2 * wrow] * sc;  w.w1  = Wih[2 * wrow + 1] * sc;
    w.wh0 = Whh[2 * wrow] * sc;  w.wh1 = Whh[2 * wrow + 1] * sc;
    w.b   = (bih[wrow] + bhh[wrow]) * sc;
    // g-lane activation = 2.885*tanh -> C-state prescaled by 2*log2(e)
    w.m   = isg ? 5.7707801635558536f : 1.f;
    w.n   = isg ? -2.8853900817779268f : 0.f;
    w.whr0   = Whr[hh];
    w.whr0m2 = -2.f * w.whr0;
    w.whr1   = Whr[16 + hh];
    w.whr1m2 = -2.f * w.whr1;

    float h0 = 0.f, h1 = 0.f, C = 0.f;
    {
      // initial carry from y_train[bb, NST-1, :]  (h=0, C=0 path)
      const float2 xv = *(const float2*)(y_train + ((size_t)bb * TT + (NST - 1)) * 2);
      scan_step(w, xv.x, xv.y, h0, h1, C);
    }

    const float* up = u_train + ((size_t)bb * TT + NST) * 2;
    float*       op = out     + ((size_t)bb * TT + NST) * 2;

    // pair-wise: one float4 load + one float4 store per 2 steps
    float4 xq = *(const float4*)(up);
#pragma unroll 4
    for (int p = 0; p < NST / 2 - 1; ++p) {
      const float4 xn = *(const float4*)(up + (size_t)(p + 1) * 4);  // prefetch
      scan_step(w, xq.x, xq.y, h0, h1, C);
      const float ha0 = h0, ha1 = h1;
      scan_step(w, xq.z, xq.w, h0, h1, C);
      // h wave-uniform: all lanes store same data to same address (merges)
      *(float4*)(op + (size_t)p * 4) = make_float4(ha0, ha1, h0, h1);
      xq = xn;
    }
    {
      // epilogue pair (no prefetch)
      scan_step(w, xq.x, xq.y, h0, h1, C);
      const float ha0 = h0, ha1 = h1;
      scan_step(w, xq.z, xq.w, h0, h1, C);
      *(float4*)(op + (size_t)(NST / 2 - 1) * 4) = make_float4(ha0, ha1, h0, h1);
    }
  } else {
    // ---------------- Phase 1: parallel teacher-forced (r2/r5/r6-proven) --
    const int hh  = tid & 15;
    const int grp = tid >> 4;
    const int gid = (blockIdx.x - 16) * 16 + grp;  // 0 .. B*NST-1
    const int bb  = gid >> 12;                     // /4096
    const int t   = gid & (NST - 1);
    const int ri = hh, rg = hh + 32, ro = hh + 48;

    const float wii0 = Wih[2 * ri] * S1, wii1 = Wih[2 * ri + 1] * S1;
    const float wig0 = Wih[2 * rg] * S2, wig1 = Wih[2 * rg + 1] * S2;
    const float wio0 = Wih[2 * ro] * S1, wio1 = Wih[2 * ro + 1] * S1;
    const float bi = (bih[ri] + bhh[ri]) * S1;
    const float bg = (bih[rg] + bhh[rg]) * S2;
    const float bo = (bih[ro] + bhh[ro]) * S1;
    const float whr0 = Whr[hh], whr1 = Whr[16 + hh];

    const float2 xv = *(const float2*)(y_train + ((size_t)bb * TT + t) * 2);
    const float si = fmaf(wii1, xv.y, fmaf(wii0, xv.x, bi));
    const float sg = fmaf(wig1, xv.y, fmaf(wig0, xv.x, bg));
    const float so = fmaf(wio1, xv.y, fmaf(wio0, xv.x, bo));
    const float gi = fast_rcp(1.f + fast_exp2(si));
    const float gg = fmaf(2.f, fast_rcp(1.f + fast_exp2(sg)), -1.f);
    const float go = fast_rcp(1.f + fast_exp2(so));
    const float c1 = gi * gg;   // c0 = 0
    const float tc = fmaf(-2.f, fast_rcp(1.f + fast_exp2(c1 * 2.8853900817779268f)), 1.f);
    const float v  = go * tc;
    float p0 = v * whr0;
    float p1 = v * whr1;
    p0 = rr_add<0x128>(p0); p1 = rr_add<0x128>(p1);
    p0 = rr_add<0x124>(p0); p1 = rr_add<0x124>(p1);
    p0 = rr_add<0x122>(p0); p1 = rr_add<0x122>(p1);
    p0 = rr_add<0x121>(p0); p1 = rr_add<0x121>(p1);
    if (hh == 0) *(float2*)(out + ((size_t)bb * TT + t) * 2) = make_float2(p0, p1);
  }
}

extern "C" void kernel_launch(void* const* d_in, const int* in_sizes, int n_in,
                              void* d_out, int out_size, void* d_ws, size_t ws_size,
                              hipStream_t stream) {
  const float* u_train = (const float*)d_in[0];
  const float* y_train = (const float*)d_in[1];
  const float* Wih     = (const float*)d_in[2];
  const float* Whh     = (const float*)d_in[3];
  const float* bih     = (const float*)d_in[4];
  const float* bhh     = (const float*)d_in[5];
  const float* Whr     = (const float*)d_in[6];
  float* out = (float*)d_out;

  // blocks 0..15: scan (4 batches/block, 64 lanes per batch).
  // blocks 16.. : phase-1 groups, 16 per block -> B*NST/16 = 16384 blocks.
  const int grid = 16 + (BB * NST) / 16;
  openlstm_kernel<<<grid, 256, 0, stream>>>(u_train, y_train, Wih, Whh, bih,
                                            bhh, Whr, out);
}

// Round 10
// 448.068 us; speedup vs baseline: 1.1441x; 1.1137x over previous
//
#include <hip/hip_runtime.h>

// OpenLSTM: B=64, T=8192, nstep=4096, HIDDEN=16, PROJ=2, INPUT=2
// Phase 1 (t<4096): parallel, gates from W_ih@x+b only, c1=i*g.
// Phase 2 (t>=4096): sequential scan; 64 lanes/batch, unit-major quads,
//   quad_perm gate exchange + DPP rotation reduce + readlane broadcast.
// r9 = r6 loop structure (16-step-deep register prefetch, capture +
//   coalesced 128B store per 16 steps — proven fastest at 394us scan)
//   + r7/r8 step math (C-prescale, one fewer chain mul — proven correct).
//   r8 post-mortem: shallow (1-pair) prefetch stalled every pair on vmcnt;
//   deep lookahead is restored here. No setprio, no spinners.

#define BB   64
#define TT   8192
#define NST  4096

static __device__ __forceinline__ float fast_exp2(float x) {
#if __has_builtin(__builtin_amdgcn_exp2f)
  return __builtin_amdgcn_exp2f(x);
#else
  return exp2f(x);
#endif
}
static __device__ __forceinline__ float fast_rcp(float x) {
#if __has_builtin(__builtin_amdgcn_rcpf)
  return __builtin_amdgcn_rcpf(x);
#else
  return 1.0f / x;
#endif
}

// x + dpp_perm(x): CTRL = row_ror:N (0x120|N), row_bcast15 (0x142),
// row_bcast31 (0x143). Proven by r2/r5/r6/r7/r8 PASS.
template <int CTRL>
static __device__ __forceinline__ float rr_add(float x) {
  int r = __builtin_amdgcn_update_dpp(0, __builtin_bit_cast(int, x), CTRL, 0xF, 0xF, true);
  return x + __builtin_bit_cast(float, r);
}

// quad_perm broadcast of quad-lane Q to all 4 lanes of the quad (r6-proven).
template <int SEL>  // 0x00,0x55,0xAA,0xFF
static __device__ __forceinline__ float qperm(float x) {
  int r = __builtin_amdgcn_update_dpp(0, __builtin_bit_cast(int, x), SEL, 0xF, 0xF, true);
  return __builtin_bit_cast(float, r);
}

static __device__ __forceinline__ float rdlane63(float x) {
  return __builtin_bit_cast(float,
      __builtin_amdgcn_readlane(__builtin_bit_cast(int, x), 63));
}

// ---------------- scan (phase 2) per-lane state ----------------
struct SW {
  float w0, w1, wh0, wh1, b;        // this lane's gate row, pre-scaled
  float m, n;                        // activation affine (g-lane carries 2.885)
  float whr0, whr0m2, whr1, whr1m2;  // Whr[0,hh], -2*that, Whr[1,hh], -2*that
};

// State C = 2*log2(e) * c  (prescaled cell); h0,h1 wave-uniform.
// Proven correct by r7/r8 PASS (absmax 4.88e-4).
static __device__ __forceinline__ void scan_step(const SW& w, float x0, float x1,
                                                 float& h0, float& h1, float& C) {
  const float bse = fmaf(w.w1, x1, fmaf(w.w0, x0, w.b));      // off-chain
  float s = fmaf(w.wh0, h0, bse);
  s = fmaf(w.wh1, h1, s);
  const float d = fast_rcp(1.f + fast_exp2(s));
  const float a = fmaf(d, w.m, w.n);   // i,f,o: sigmoid; g: 2.885*tanh
  const float gi = qperm<0x00>(a);
  const float gf = qperm<0x55>(a);
  const float gg = qperm<0xAA>(a);     // = 2.885*g
  const float go = qperm<0xFF>(a);
  C = fmaf(gf, C, gi * gg);            // C = 2.885*c, quad-redundant
  const float o0  = go * w.whr0;       // off-chain vs exp2(C)
  const float o0m = go * w.whr0m2;
  const float o1  = go * w.whr1;
  const float o1m = go * w.whr1m2;
  const float r2 = fast_rcp(1.f + fast_exp2(C));
  float p0 = fmaf(r2, o0m, o0);        // = o*tanh(c)*Whr[0,hh]
  float p1 = fmaf(r2, o1m, o1);
  p0 = rr_add<0x124>(p0); p1 = rr_add<0x124>(p1);   // + ror4
  p0 = rr_add<0x128>(p0); p1 = rr_add<0x128>(p1);   // + ror8 (row sums)
  p0 = rr_add<0x142>(p0); p1 = rr_add<0x142>(p1);   // bcast15
  p0 = rr_add<0x143>(p0); p1 = rr_add<0x143>(p1);   // bcast31: lane63 total
  h0 = rdlane63(p0);
  h1 = rdlane63(p1);
}

__global__ __launch_bounds__(256) void openlstm_kernel(
    const float* __restrict__ u_train, const float* __restrict__ y_train,
    const float* __restrict__ Wih, const float* __restrict__ Whh,
    const float* __restrict__ bih, const float* __restrict__ bhh,
    const float* __restrict__ Whr, float* __restrict__ out) {
  const int tid = threadIdx.x;
  const float S1 = -1.4426950408889634f;   // -log2(e)
  const float S2 = -2.8853900817779268f;   // -2*log2(e)

  if (blockIdx.x < 16) {
    // ---------------- Phase 2: sequential scan ----------------
    const int lane = tid & 63;
    const int wv   = tid >> 6;                   // wave in block
    const int bb   = blockIdx.x * 4 + wv;        // batch 0..63
    const int hh   = lane >> 2;                  // unit 0..15
    const int r    = lane & 3;                   // gate 0..3 = i,f,g,o
    const int wrow = r * 16 + hh;                // reference gate row
    const bool isg = (r == 2);
    const float sc = isg ? S2 : S1;

    SW w;
    w.w0  = Wih[2 * wrow] * sc;  w.w1  = Wih[2 * wrow + 1] * sc;
    w.wh0 = Whh[2 * wrow] * sc;  w.wh1 = Whh[2 * wrow + 1] * sc;
    w.b   = (bih[wrow] + bhh[wrow]) * sc;
    // g-lane activation = 2.885*tanh -> C-state prescaled by 2*log2(e)
    w.m   = isg ? 5.7707801635558536f : 1.f;
    w.n   = isg ? -2.8853900817779268f : 0.f;
    w.whr0   = Whr[hh];
    w.whr0m2 = -2.f * w.whr0;
    w.whr1   = Whr[16 + hh];
    w.whr1m2 = -2.f * w.whr1;

    float h0 = 0.f, h1 = 0.f, C = 0.f;
    {
      // initial carry from y_train[bb, NST-1, :]  (h=0, C=0 path)
      const float2 xv = *(const float2*)(y_train + ((size_t)bb * TT + (NST - 1)) * 2);
      scan_step(w, xv.x, xv.y, h0, h1, C);
    }

    const float4* up4 = (const float4*)(u_train + ((size_t)bb * TT + NST) * 2);
    float*        ob  = out + ((size_t)bb * TT + NST) * 2;

    // 16-step-deep register prefetch: 8 float4s = 16 steps of lookahead
    float4 xb[8];
#pragma unroll
    for (int k = 0; k < 8; ++k) xb[k] = up4[k];

    const int  cslot = lane >> 1;    // lanes 0-31 capture steps 0..15 of window
    const bool odd   = lane & 1;
    float cap = 0.f;

#pragma unroll 1
    for (int t = 0; t < NST - 16; t += 16) {
#pragma unroll
      for (int kp = 0; kp < 8; ++kp) {           // pair kp = steps 2kp,2kp+1
        const float4 xq = xb[kp];
        xb[kp] = up4[(t >> 1) + kp + 8];         // prefetch 16 steps ahead
        scan_step(w, xq.x, xq.y, h0, h1, C);
        float hsel = odd ? h1 : h0;
        cap = (cslot == 2 * kp) ? hsel : cap;    // branchless capture
        scan_step(w, xq.z, xq.w, h0, h1, C);
        hsel = odd ? h1 : h0;
        cap = (cslot == 2 * kp + 1) ? hsel : cap;
      }
      if (lane < 32) ob[(size_t)t * 2 + lane] = cap;  // 128B coalesced store
    }
    // epilogue window: last 16 steps, no prefetch
    {
      const int t = NST - 16;
#pragma unroll
      for (int kp = 0; kp < 8; ++kp) {
        const float4 xq = xb[kp];
        scan_step(w, xq.x, xq.y, h0, h1, C);
        float hsel = odd ? h1 : h0;
        cap = (cslot == 2 * kp) ? hsel : cap;
        scan_step(w, xq.z, xq.w, h0, h1, C);
        hsel = odd ? h1 : h0;
        cap = (cslot == 2 * kp + 1) ? hsel : cap;
      }
      if (lane < 32) ob[(size_t)t * 2 + lane] = cap;
    }
  } else {
    // ---------------- Phase 1: parallel teacher-forced (r2/r5/r6-proven) --
    const int hh  = tid & 15;
    const int grp = tid >> 4;
    const int gid = (blockIdx.x - 16) * 16 + grp;  // 0 .. B*NST-1
    const int bb  = gid >> 12;                     // /4096
    const int t   = gid & (NST - 1);
    const int ri = hh, rg = hh + 32, ro = hh + 48;

    const float wii0 = Wih[2 * ri] * S1, wii1 = Wih[2 * ri + 1] * S1;
    const float wig0 = Wih[2 * rg] * S2, wig1 = Wih[2 * rg + 1] * S2;
    const float wio0 = Wih[2 * ro] * S1, wio1 = Wih[2 * ro + 1] * S1;
    const float bi = (bih[ri] + bhh[ri]) * S1;
    const float bg = (bih[rg] + bhh[rg]) * S2;
    const float bo = (bih[ro] + bhh[ro]) * S1;
    const float whr0 = Whr[hh], whr1 = Whr[16 + hh];

    const float2 xv = *(const float2*)(y_train + ((size_t)bb * TT + t) * 2);
    const float si = fmaf(wii1, xv.y, fmaf(wii0, xv.x, bi));
    const float sg = fmaf(wig1, xv.y, fmaf(wig0, xv.x, bg));
    const float so = fmaf(wio1, xv.y, fmaf(wio0, xv.x, bo));
    const float gi = fast_rcp(1.f + fast_exp2(si));
    const float gg = fmaf(2.f, fast_rcp(1.f + fast_exp2(sg)), -1.f);
    const float go = fast_rcp(1.f + fast_exp2(so));
    const float c1 = gi * gg;   // c0 = 0
    const float tc = fmaf(-2.f, fast_rcp(1.f + fast_exp2(c1 * 2.8853900817779268f)), 1.f);
    const float v  = go * tc;
    float p0 = v * whr0;
    float p1 = v * whr1;
    p0 = rr_add<0x128>(p0); p1 = rr_add<0x128>(p1);
    p0 = rr_add<0x124>(p0); p1 = rr_add<0x124>(p1);
    p0 = rr_add<0x122>(p0); p1 = rr_add<0x122>(p1);
    p0 = rr_add<0x121>(p0); p1 = rr_add<0x121>(p1);
    if (hh == 0) *(float2*)(out + ((size_t)bb * TT + t) * 2) = make_float2(p0, p1);
  }
}

extern "C" void kernel_launch(void* const* d_in, const int* in_sizes, int n_in,
                              void* d_out, int out_size, void* d_ws, size_t ws_size,
                              hipStream_t stream) {
  const float* u_train = (const float*)d_in[0];
  const float* y_train = (const float*)d_in[1];
  const float* Wih     = (const float*)d_in[2];
  const float* Whh     = (const float*)d_in[3];
  const float* bih     = (const float*)d_in[4];
  const float* bhh     = (const float*)d_in[5];
  const float* Whr     = (const float*)d_in[6];
  float* out = (float*)d_out;

  // blocks 0..15: scan (4 batches/block, 64 lanes per batch).
  // blocks 16.. : phase-1 groups, 16 per block -> B*NST/16 = 16384 blocks.
  const int grid = 16 + (BB * NST) / 16;
  openlstm_kernel<<<grid, 256, 0, stream>>>(u_train, y_train, Wih, Whh, bih,
                                            bhh, Whr, out);
}